// Round 3
// baseline (209.579 us; speedup 1.0000x reference)
//
#include <hip/hip_runtime.h>
#include <cmath>

#define NR 65536
#define DIM 512
#define KC 128
#define SLICES 4
#define SCOLS 128   // columns per slice

// Native LDS float atomic add: relaxed, workgroup scope -> ds_add_f32.
__device__ __forceinline__ void lds_fadd(float* p, float v) {
    __hip_atomic_fetch_add(p, v, __ATOMIC_RELAXED, __HIP_MEMORY_SCOPE_WORKGROUP);
}

// ---------------------------------------------------------------------------
// Kernel 0: class counts. int4 loads, LDS int histogram (native ds_add_u32),
// one global int atomicAdd per class per block (exact -> deterministic).
// ---------------------------------------------------------------------------
__global__ __launch_bounds__(256) void vmf_count(
    const int* __restrict__ y, int* __restrict__ ncount)
{
    __shared__ int cnt[KC];
    const int t = threadIdx.x;
    if (t < KC) cnt[t] = 0;
    __syncthreads();
    const int4 v = ((const int4*)y)[blockIdx.x * 256 + t];
    atomicAdd(&cnt[v.x], 1);
    atomicAdd(&cnt[v.y], 1);
    atomicAdd(&cnt[v.z], 1);
    atomicAdd(&cnt[v.w], 1);
    __syncthreads();
    if (t < KC) atomicAdd(&ncount[t], cnt[t]);
}

// ---------------------------------------------------------------------------
// Kernel A: segment sum. grid = (4 col-slices, nchunks), 512 threads,
// 64 KB LDS tile [128 classes][128 cols], 2 blocks/CU -> 16 waves/CU.
// Wave macro-tile = 16 rows: 1 lane-resident y load (classes via __shfl),
// 8 float4 X loads (2 rows x 512B each), then swizzled ds_add_f32 with
// exactly 2 lanes/bank (free per m136).
// ---------------------------------------------------------------------------
__global__ __launch_bounds__(512, 4) void vmf_segsum(
    const float* __restrict__ X, const int* __restrict__ y,
    float* __restrict__ partial, int rows_per_chunk)
{
    __shared__ float acc[KC * SCOLS];          // 64 KB
    const int tid   = threadIdx.x;
    const int lane  = tid & 63;
    const int w     = tid >> 6;                // 8 waves
    const int slice = blockIdx.x;
    const int chunk = blockIdx.y;
    const int d0    = slice * SCOLS;

    for (int i = tid; i < KC * SCOLS / 4; i += 512)
        ((float4*)acc)[i] = make_float4(0.f, 0.f, 0.f, 0.f);
    __syncthreads();

    const int cl = lane & 31;                  // column-quad index within row
    const int g  = lane >> 5;                  // row sub-group (0/1)
    const int r0 = chunk * rows_per_chunk;
    const int r1 = r0 + rows_per_chunk;        // multiple of 16 (pow2 chunks)

    for (int rb = r0 + w * 16; rb < r1; rb += 128) {
        const int yv = y[rb + (lane & 15)];    // 16 classes, lane-resident
        float4 xv[8];
        #pragma unroll
        for (int gg = 0; gg < 8; ++gg) {
            const int row = rb + 2 * gg + g;
            xv[gg] = *(const float4*)(X + (size_t)row * DIM + d0 + cl * 4);
        }
        #pragma unroll
        for (int gg = 0; gg < 8; ++gg) {
            const int c = __shfl(yv, 2 * gg + g);
            float* a = &acc[c * SCOLS + cl];
            lds_fadd(a +  0, xv[gg].x);
            lds_fadd(a + 32, xv[gg].y);
            lds_fadd(a + 64, xv[gg].z);
            lds_fadd(a + 96, xv[gg].w);
        }
    }
    __syncthreads();

    for (int i = tid; i < KC * SCOLS; i += 512) {
        const int c = i >> 7, col = i & 127;
        partial[(size_t)(chunk * KC + c) * DIM + d0 + col] =
            acc[c * SCOLS + ((col & 3) << 5) + (col >> 2)];
    }
}

// ---------------------------------------------------------------------------
// Kernel B: reduce partials -> r[K][D]; per-class norm, kappa, logk, ive.
// 128 blocks x 1024 threads; thread (cg,q) sums chunk-stripe cg (of 8) over
// float4 column q -> up to 16 independent float4 loads each.
// ---------------------------------------------------------------------------
__global__ __launch_bounds__(1024) void vmf_reduce(
    const float* __restrict__ partial, const int* __restrict__ ncount,
    float* __restrict__ r, float* __restrict__ kappa, float* __restrict__ logk,
    float* __restrict__ bes, float* __restrict__ innorm, int nchunks)
{
    const int k = blockIdx.x, t = threadIdx.x;
    const int q  = t & 127;                    // float4 column
    const int cg = t >> 7;                     // chunk stripe 0..7
    float4 s = make_float4(0.f, 0.f, 0.f, 0.f);
    for (int c = cg; c < nchunks; c += 8) {
        const float4 v = ((const float4*)(partial + (size_t)(c * KC + k) * DIM))[q];
        s.x += v.x; s.y += v.y; s.z += v.z; s.w += v.w;
    }
    __shared__ float4 red[1024];               // 16 KB
    red[t] = s;
    __syncthreads();

    float ss = 0.f;
    if (t < 128) {
        float4 tot = red[t];
        #pragma unroll
        for (int sIdx = 1; sIdx < 8; ++sIdx) {
            const float4 v = red[t + 128 * sIdx];
            tot.x += v.x; tot.y += v.y; tot.z += v.z; tot.w += v.w;
        }
        ((float4*)(r + (size_t)k * DIM))[t] = tot;
        ss = tot.x * tot.x + tot.y * tot.y + tot.z * tot.z + tot.w * tot.w;
    }
    for (int off = 32; off; off >>= 1) ss += __shfl_down(ss, off);
    __shared__ float wsum[16];
    if ((t & 63) == 0) wsum[t >> 6] = ss;
    __syncthreads();
    if (t == 0) {
        const float tot  = wsum[0] + wsum[1];
        const float norm = sqrtf(tot);
        const float nk   = (float)ncount[k];
        const float rb   = norm / nk;
        float kap = ((float)DIM * rb - rb * rb * rb) / (1.f - rb * rb);
        if (rb > 0.9f) kap = -0.4f + 1.39f * rb + 0.43f / (1.f - rb);
        kappa[k] = kap;
        logk[k]  = logf(kap);
        const float v  = 255.5f;
        const float zz = kap / v;
        const float sq = sqrtf(1.f + zz * zz);
        const float tt = 1.f / sq, t2 = tt * tt;
        const float eta = sq + logf(zz / (1.f + sq));
        const float u1 = (3.f * tt - 5.f * tt * t2) / 24.f;
        const float u2 = (81.f * t2 - 462.f * t2 * t2 + 385.f * t2 * t2 * t2) / 1152.f;
        const float u3 = (30375.f * tt * t2 - 369603.f * tt * t2 * t2
                    + 765765.f * tt * t2 * t2 * t2
                    - 425425.f * tt * t2 * t2 * t2 * t2) / 414720.f;
        const float series = 1.f + u1 / v + u2 / (v * v) + u3 / (v * v * v);
        const float ive = expf(v * eta - kap) * series
                    / (sqrtf(2.f * 3.14159265358979f * v) * sqrtf(sq));
        bes[k] = ive;
        innorm[k] = 1.f / norm;
    }
}

// ---------------------------------------------------------------------------
// Kernel C: block i computes kl[i][j]^2 for all j, reduces to rowsum[i].
// ---------------------------------------------------------------------------
__global__ __launch_bounds__(128) void vmf_gram(
    const float* __restrict__ r, const float* __restrict__ kappa,
    const float* __restrict__ logk, const float* __restrict__ bes,
    const float* __restrict__ innorm, float* __restrict__ rowsum)
{
    const int i = blockIdx.x, j = threadIdx.x;
    __shared__ float mui[DIM];
    const float inv_i = innorm[i];
    for (int d = j; d < DIM; d += 128) mui[d] = r[(size_t)i * DIM + d] * inv_i;
    __syncthreads();

    const float4* rj = (const float4*)(r + (size_t)j * DIM);
    float acc = 0.f;
    #pragma unroll 4
    for (int d4 = 0; d4 < DIM / 4; ++d4) {
        float4 v = rj[d4];
        acc += mui[d4 * 4 + 0] * v.x + mui[d4 * 4 + 1] * v.y
             + mui[d4 * 4 + 2] * v.z + mui[d4 * 4 + 3] * v.w;
    }
    const float dot = acc * innorm[j];
    const float dstar = 255.5f;
    float kl = dstar * (logk[j] - logk[i]) - kappa[i] + bes[i] - bes[j]
             + kappa[j] * dot;
    float v2 = kl * kl;
    for (int off = 32; off; off >>= 1) v2 += __shfl_down(v2, off);
    __shared__ float ws2[2];
    if ((j & 63) == 0) ws2[j >> 6] = v2;
    __syncthreads();
    if (j == 0) rowsum[i] = ws2[0] + ws2[1];
}

// ---------------------------------------------------------------------------
// Kernel D: sum 128 row sums -> out[0] = total / K^2
// ---------------------------------------------------------------------------
__global__ __launch_bounds__(128) void vmf_final(
    const float* __restrict__ rowsum, float* __restrict__ out)
{
    const int t = threadIdx.x;
    float v = rowsum[t];
    for (int off = 32; off; off >>= 1) v += __shfl_down(v, off);
    __shared__ float w[2];
    if ((t & 63) == 0) w[t >> 6] = v;
    __syncthreads();
    if (t == 0) out[0] = (w[0] + w[1]) / (float)(KC * KC);
}

extern "C" void kernel_launch(void* const* d_in, const int* in_sizes, int n_in,
                              void* d_out, int out_size, void* d_ws, size_t ws_size,
                              hipStream_t stream)
{
    const float* X = (const float*)d_in[0];
    const int*   y = (const int*)d_in[1];
    float* out = (float*)d_out;
    float* ws  = (float*)d_ws;

    // workspace layout (float units)
    float* r      = ws;                    // 65536
    float* kappa  = ws + 65536;            // 128
    float* logk   = ws + 65536 + 128;
    float* bes    = ws + 65536 + 256;
    float* innorm = ws + 65536 + 384;
    float* rowsum = ws + 65536 + 512;
    int*   ncount = (int*)(ws + 65536 + 640);   // 128 ints
    float* partial = ws + 66560;           // nchunks * KC * DIM

    const size_t avail = ws_size / 4;
    int nchunks = 128;                     // grid 512 blocks -> 2 blocks/CU
    while (nchunks > 1 &&
           (size_t)66560 + (size_t)nchunks * KC * DIM > avail)
        nchunks >>= 1;
    const int rows_per_chunk = NR / nchunks;   // multiple of 16 (pow2 chunks)

    hipMemsetAsync(ncount, 0, KC * sizeof(int), stream);
    vmf_count<<<NR / 4 / 256, 256, 0, stream>>>(y, ncount);
    dim3 gA(SLICES, nchunks);
    vmf_segsum<<<gA, 512, 0, stream>>>(X, y, partial, rows_per_chunk);
    vmf_reduce<<<KC, 1024, 0, stream>>>(partial, ncount, r, kappa, logk, bes,
                                        innorm, nchunks);
    vmf_gram<<<KC, 128, 0, stream>>>(r, kappa, logk, bes, innorm, rowsum);
    vmf_final<<<1, 128, 0, stream>>>(rowsum, out);
}

// Round 4
// 54.952 us; speedup vs baseline: 3.8139x; 3.8139x over previous
//
#include <hip/hip_runtime.h>
#include <cmath>

#define NR 65536
#define DIM 512
#define KC 128
#define NPART 4
#define PART_ROWS (NR / NPART)            // 16384 rows per quarter
#define WAVE_ROWS (PART_ROWS / 8)         // 2048 rows scanned per wave
#define CHUNKS_PER_WAVE (WAVE_ROWS / 64)  // 32 ballot masks per wave
#define LIST_CAP 768                      // mean 128, sd ~11 -> never trips

// ---------------------------------------------------------------------------
// Kernel A: per-(class, quarter) scan + gather segment sum. No atomics in the
// float path. 512 blocks x 512 threads.
//  Phase 1: int4 scan of the y-quarter, __ballot masks -> LDS (deterministic).
//  Phase 2: ordered compaction of masks -> row-id list in LDS.
//  Phase 3: 8 waves = (4 col-strips x 2 row-parities); coalesced float2
//           gathers of 512B row slices, register accumulation, LDS pair-
//           reduce, write partial[h][k][512].
// ---------------------------------------------------------------------------
__global__ __launch_bounds__(512, 2) void vmf_scan_sum(
    const float* __restrict__ X, const int* __restrict__ y,
    float* __restrict__ partial, int* __restrict__ ncount)
{
    __shared__ unsigned long long masks[8 * CHUNKS_PER_WAVE]; // 2 KB
    __shared__ unsigned short list[LIST_CAP];                 // 1.5 KB
    __shared__ int wcnt[8];
    __shared__ float red[8][128];                             // 4 KB

    const int tid  = threadIdx.x;
    const int lane = tid & 63;
    const int w    = tid >> 6;                 // wave 0..7
    const int k    = blockIdx.x & (KC - 1);    // class
    const int h    = blockIdx.x >> 7;          // quarter
    const int wbase = h * PART_ROWS + w * WAVE_ROWS;

    // ---- Phase 1: ballot scan ----
    int cnt = 0;
    #pragma unroll
    for (int it = 0; it < WAVE_ROWS / 256; ++it) {     // 8 iters
        const int4 v = *(const int4*)(y + wbase + it * 256 + lane * 4);
        const unsigned long long m0 = __ballot(v.x == k);
        const unsigned long long m1 = __ballot(v.y == k);
        const unsigned long long m2 = __ballot(v.z == k);
        const unsigned long long m3 = __ballot(v.w == k);
        if (lane == 0) {
            masks[w * CHUNKS_PER_WAVE + it * 4 + 0] = m0;
            masks[w * CHUNKS_PER_WAVE + it * 4 + 1] = m1;
            masks[w * CHUNKS_PER_WAVE + it * 4 + 2] = m2;
            masks[w * CHUNKS_PER_WAVE + it * 4 + 3] = m3;
        }
        cnt += __popcll(m0) + __popcll(m1) + __popcll(m2) + __popcll(m3);
    }
    if (lane == 0) wcnt[w] = cnt;
    __syncthreads();

    int base = 0, ntot = 0;
    #pragma unroll
    for (int w2 = 0; w2 < 8; ++w2) {
        const int c = wcnt[w2];
        if (w2 < w) base += c;
        ntot += c;
    }
    if (ntot > LIST_CAP) ntot = LIST_CAP;      // statistical impossibility guard
    if (tid == 0) atomicAdd(&ncount[k], ntot); // exact int, order-independent

    // ---- Phase 2: ordered compaction (mask bit l of chunk c=(it,j)
    //      is row wbase + it*256 + lane*4 + j) ----
    {
        int b = base;
        const unsigned long long lt = (1ULL << lane) - 1ULL;
        for (int c = 0; c < CHUNKS_PER_WAVE; ++c) {
            const unsigned long long m = masks[w * CHUNKS_PER_WAVE + c];
            const int pos = b + __popcll(m & lt);
            if (((m >> lane) & 1ULL) && pos < LIST_CAP) {
                const int it = c >> 2, j = c & 3;
                list[pos] = (unsigned short)(wbase + it * 256 + lane * 4 + j);
            }
            b += __popcll(m);
        }
    }
    __syncthreads();

    // ---- Phase 3: gather-sum. wave -> (col-strip cs, parity p) ----
    const int cs = w & 3;                       // float cols [cs*128, +128)
    const int p  = w >> 2;                      // list-slot parity
    const float* Xs = X + cs * 128 + lane * 2;  // float2 per lane

    float2 a0 = {0.f, 0.f}, a1 = {0.f, 0.f}, a2 = {0.f, 0.f}, a3 = {0.f, 0.f};
    float2 a4 = {0.f, 0.f}, a5 = {0.f, 0.f}, a6 = {0.f, 0.f}, a7 = {0.f, 0.f};
    int i = p;
    for (; i + 14 < ntot; i += 16) {            // 8 slots of this parity
        const int r0 = list[i];      const int r1 = list[i + 2];
        const int r2 = list[i + 4];  const int r3 = list[i + 6];
        const int r4 = list[i + 8];  const int r5 = list[i + 10];
        const int r6 = list[i + 12]; const int r7 = list[i + 14];
        const float2 v0 = *(const float2*)(Xs + (size_t)r0 * DIM);
        const float2 v1 = *(const float2*)(Xs + (size_t)r1 * DIM);
        const float2 v2 = *(const float2*)(Xs + (size_t)r2 * DIM);
        const float2 v3 = *(const float2*)(Xs + (size_t)r3 * DIM);
        const float2 v4 = *(const float2*)(Xs + (size_t)r4 * DIM);
        const float2 v5 = *(const float2*)(Xs + (size_t)r5 * DIM);
        const float2 v6 = *(const float2*)(Xs + (size_t)r6 * DIM);
        const float2 v7 = *(const float2*)(Xs + (size_t)r7 * DIM);
        a0.x += v0.x; a0.y += v0.y;  a1.x += v1.x; a1.y += v1.y;
        a2.x += v2.x; a2.y += v2.y;  a3.x += v3.x; a3.y += v3.y;
        a4.x += v4.x; a4.y += v4.y;  a5.x += v5.x; a5.y += v5.y;
        a6.x += v6.x; a6.y += v6.y;  a7.x += v7.x; a7.y += v7.y;
    }
    for (; i < ntot; i += 2) {
        const int r = list[i];
        const float2 v = *(const float2*)(Xs + (size_t)r * DIM);
        a0.x += v.x; a0.y += v.y;
    }
    float2 a;
    a.x = ((a0.x + a1.x) + (a2.x + a3.x)) + ((a4.x + a5.x) + (a6.x + a7.x));
    a.y = ((a0.y + a1.y) + (a2.y + a3.y)) + ((a4.y + a5.y) + (a6.y + a7.y));
    red[w][lane * 2 + 0] = a.x;
    red[w][lane * 2 + 1] = a.y;
    __syncthreads();

    // fold parities, write partial
    const int cs2 = tid >> 7, c2 = tid & 127;
    partial[(size_t)(h * KC + k) * DIM + cs2 * 128 + c2] =
        red[cs2][c2] + red[cs2 + 4][c2];
}

// ---------------------------------------------------------------------------
// Kernel B: fold 4 quarter-partials -> r[K][D]; norm, kappa, logk, ive.
// 128 blocks x 512 threads (thread = column).
// ---------------------------------------------------------------------------
__global__ __launch_bounds__(512) void vmf_reduce2(
    const float* __restrict__ partial, const int* __restrict__ ncount,
    float* __restrict__ r, float* __restrict__ kappa, float* __restrict__ logk,
    float* __restrict__ bes, float* __restrict__ innorm)
{
    const int k = blockIdx.x, t = threadIdx.x;
    float s = 0.f;
    #pragma unroll
    for (int hh = 0; hh < NPART; ++hh)
        s += partial[(size_t)(hh * KC + k) * DIM + t];
    r[(size_t)k * DIM + t] = s;

    float ss = s * s;
    for (int off = 32; off; off >>= 1) ss += __shfl_down(ss, off);
    __shared__ float wsum[8];
    if ((t & 63) == 0) wsum[t >> 6] = ss;
    __syncthreads();
    if (t == 0) {
        float tot = 0.f;
        #pragma unroll
        for (int q = 0; q < 8; ++q) tot += wsum[q];
        const float norm = sqrtf(tot);
        const float nk   = (float)ncount[k];
        const float rb   = norm / nk;
        float kap = ((float)DIM * rb - rb * rb * rb) / (1.f - rb * rb);
        if (rb > 0.9f) kap = -0.4f + 1.39f * rb + 0.43f / (1.f - rb);
        kappa[k] = kap;
        logk[k]  = logf(kap);
        const float v  = 255.5f;
        const float zz = kap / v;
        const float sq = sqrtf(1.f + zz * zz);
        const float tt = 1.f / sq, t2 = tt * tt;
        const float eta = sq + logf(zz / (1.f + sq));
        const float u1 = (3.f * tt - 5.f * tt * t2) / 24.f;
        const float u2 = (81.f * t2 - 462.f * t2 * t2 + 385.f * t2 * t2 * t2) / 1152.f;
        const float u3 = (30375.f * tt * t2 - 369603.f * tt * t2 * t2
                    + 765765.f * tt * t2 * t2 * t2
                    - 425425.f * tt * t2 * t2 * t2 * t2) / 414720.f;
        const float series = 1.f + u1 / v + u2 / (v * v) + u3 / (v * v * v);
        const float ive = expf(v * eta - kap) * series
                    / (sqrtf(2.f * 3.14159265358979f * v) * sqrtf(sq));
        bes[k] = ive;
        innorm[k] = 1.f / norm;
    }
}

// ---------------------------------------------------------------------------
// Kernel C: block i computes kl[i][j]^2 for all j, reduces to rowsum[i].
// ---------------------------------------------------------------------------
__global__ __launch_bounds__(128) void vmf_gram(
    const float* __restrict__ r, const float* __restrict__ kappa,
    const float* __restrict__ logk, const float* __restrict__ bes,
    const float* __restrict__ innorm, float* __restrict__ rowsum)
{
    const int i = blockIdx.x, j = threadIdx.x;
    __shared__ float mui[DIM];
    const float inv_i = innorm[i];
    for (int d = j; d < DIM; d += 128) mui[d] = r[(size_t)i * DIM + d] * inv_i;
    __syncthreads();

    const float4* rj = (const float4*)(r + (size_t)j * DIM);
    float acc = 0.f;
    #pragma unroll 4
    for (int d4 = 0; d4 < DIM / 4; ++d4) {
        float4 v = rj[d4];
        acc += mui[d4 * 4 + 0] * v.x + mui[d4 * 4 + 1] * v.y
             + mui[d4 * 4 + 2] * v.z + mui[d4 * 4 + 3] * v.w;
    }
    const float dot = acc * innorm[j];
    const float dstar = 255.5f;
    float kl = dstar * (logk[j] - logk[i]) - kappa[i] + bes[i] - bes[j]
             + kappa[j] * dot;
    float v2 = kl * kl;
    for (int off = 32; off; off >>= 1) v2 += __shfl_down(v2, off);
    __shared__ float ws2[2];
    if ((j & 63) == 0) ws2[j >> 6] = v2;
    __syncthreads();
    if (j == 0) rowsum[i] = ws2[0] + ws2[1];
}

// ---------------------------------------------------------------------------
// Kernel D: sum 128 row sums -> out[0] = total / K^2
// ---------------------------------------------------------------------------
__global__ __launch_bounds__(128) void vmf_final(
    const float* __restrict__ rowsum, float* __restrict__ out)
{
    const int t = threadIdx.x;
    float v = rowsum[t];
    for (int off = 32; off; off >>= 1) v += __shfl_down(v, off);
    __shared__ float w[2];
    if ((t & 63) == 0) w[t >> 6] = v;
    __syncthreads();
    if (t == 0) out[0] = (w[0] + w[1]) / (float)(KC * KC);
}

extern "C" void kernel_launch(void* const* d_in, const int* in_sizes, int n_in,
                              void* d_out, int out_size, void* d_ws, size_t ws_size,
                              hipStream_t stream)
{
    const float* X = (const float*)d_in[0];
    const int*   y = (const int*)d_in[1];
    float* out = (float*)d_out;
    float* ws  = (float*)d_ws;

    // workspace layout (float units)
    float* r      = ws;                         // 65536
    float* kappa  = ws + 65536;                 // 128
    float* logk   = ws + 65536 + 128;
    float* bes    = ws + 65536 + 256;
    float* innorm = ws + 65536 + 384;
    float* rowsum = ws + 65536 + 512;
    int*   ncount = (int*)(ws + 65536 + 640);   // 128 ints
    float* partial = ws + 66560;                // NPART*KC*DIM = 262144 floats

    hipMemsetAsync(ncount, 0, KC * sizeof(int), stream);
    vmf_scan_sum<<<KC * NPART, 512, 0, stream>>>(X, y, partial, ncount);
    vmf_reduce2<<<KC, 512, 0, stream>>>(partial, ncount, r, kappa, logk, bes,
                                        innorm);
    vmf_gram<<<KC, 128, 0, stream>>>(r, kappa, logk, bes, innorm, rowsum);
    vmf_final<<<1, 128, 0, stream>>>(rowsum, out);
}

// Round 6
// 49.656 us; speedup vs baseline: 4.2206x; 1.1067x over previous
//
#include <hip/hip_runtime.h>
#include <cmath>

#define NR 65536
#define DIM 512
#define KC 128
#define NPART 4
#define PART_ROWS (NR / NPART)            // 16384 rows per quarter
#define WAVE_ROWS (PART_ROWS / 8)         // 2048 rows scanned per wave
#define CHUNKS_PER_WAVE (WAVE_ROWS / 64)  // 32 ballot masks per wave
#define LIST_CAP 768                      // mean 128, sd ~11 -> never trips

// ---------------------------------------------------------------------------
// Kernel A: per-(class, quarter) scan + gather segment sum. No atomics at all.
// 512 blocks x 512 threads.
//  Phase 1: int4 scan of the y-quarter, __ballot masks -> LDS (deterministic).
//  Phase 2: ordered compaction of masks -> row-id list in LDS.
//  Phase 3: 8 waves = (4 col-strips x 2 slot-parities); each load = 32 lanes
//           x float4 = one full 512B row-strip, 2 rows per load instruction,
//           8 loads in flight -> 16 rows/iter/wave. Register accumulation,
//           LDS reduce, write partial[h][k][512] and pcount[h][k].
// ---------------------------------------------------------------------------
__global__ __launch_bounds__(512, 2) void vmf_scan_sum(
    const float* __restrict__ X, const int* __restrict__ y,
    float* __restrict__ partial, int* __restrict__ pcount)
{
    __shared__ unsigned long long masks[8 * CHUNKS_PER_WAVE]; // 2 KB
    __shared__ unsigned short list[LIST_CAP];                 // 1.5 KB
    __shared__ int wcnt[8];
    __shared__ float4 sred[8][2][32];                         // 8 KB

    const int tid  = threadIdx.x;
    const int lane = tid & 63;
    const int w    = tid >> 6;                 // wave 0..7
    const int k    = blockIdx.x & (KC - 1);    // class
    const int h    = blockIdx.x >> 7;          // quarter
    const int wbase = h * PART_ROWS + w * WAVE_ROWS;

    // ---- Phase 1: ballot scan ----
    int cnt = 0;
    #pragma unroll
    for (int it = 0; it < WAVE_ROWS / 256; ++it) {     // 8 iters
        const int4 v = *(const int4*)(y + wbase + it * 256 + lane * 4);
        const unsigned long long m0 = __ballot(v.x == k);
        const unsigned long long m1 = __ballot(v.y == k);
        const unsigned long long m2 = __ballot(v.z == k);
        const unsigned long long m3 = __ballot(v.w == k);
        if (lane == 0) {
            masks[w * CHUNKS_PER_WAVE + it * 4 + 0] = m0;
            masks[w * CHUNKS_PER_WAVE + it * 4 + 1] = m1;
            masks[w * CHUNKS_PER_WAVE + it * 4 + 2] = m2;
            masks[w * CHUNKS_PER_WAVE + it * 4 + 3] = m3;
        }
        cnt += __popcll(m0) + __popcll(m1) + __popcll(m2) + __popcll(m3);
    }
    if (lane == 0) wcnt[w] = cnt;
    __syncthreads();

    int base = 0, ntot = 0;
    #pragma unroll
    for (int w2 = 0; w2 < 8; ++w2) {
        const int c = wcnt[w2];
        if (w2 < w) base += c;
        ntot += c;
    }
    if (ntot > LIST_CAP) ntot = LIST_CAP;      // statistical impossibility guard

    // ---- Phase 2: ordered compaction (mask bit l of chunk c=(it,j)
    //      is row wbase + it*256 + lane*4 + j) ----
    {
        int b = base;
        const unsigned long long lt = (1ULL << lane) - 1ULL;
        for (int c = 0; c < CHUNKS_PER_WAVE; ++c) {
            const unsigned long long m = masks[w * CHUNKS_PER_WAVE + c];
            const int pos = b + __popcll(m & lt);
            if (((m >> lane) & 1ULL) && pos < LIST_CAP) {
                const int it = c >> 2, j = c & 3;
                list[pos] = (unsigned short)(wbase + it * 256 + lane * 4 + j);
            }
            b += __popcll(m);
        }
    }
    __syncthreads();

    // ---- Phase 3: gather-sum. wave -> (col-strip cs, parity p);
    //      half-wave pr=lane>>5 takes slot 2*(2j+pr) within the batch. ----
    const int cs = w & 3;                       // float cols [cs*128, +128)
    const int p  = w >> 2;                      // list-slot parity
    const int pr = lane >> 5;                   // half-wave row select
    const int c4 = lane & 31;                   // float4 column within strip
    const float* Xs = X + cs * 128 + c4 * 4;

    float4 acc[8];
    #pragma unroll
    for (int j = 0; j < 8; ++j) acc[j] = make_float4(0.f, 0.f, 0.f, 0.f);

    int i = p;
    for (; i + 30 < ntot; i += 32) {            // 16 rows per iter per wave
        int rows[8];
        #pragma unroll
        for (int j = 0; j < 8; ++j) rows[j] = list[i + 2 * (2 * j + pr)];
        float4 v[8];
        #pragma unroll
        for (int j = 0; j < 8; ++j)
            v[j] = *(const float4*)(Xs + (size_t)rows[j] * DIM);
        #pragma unroll
        for (int j = 0; j < 8; ++j) {
            acc[j].x += v[j].x; acc[j].y += v[j].y;
            acc[j].z += v[j].z; acc[j].w += v[j].w;
        }
    }
    for (; i < ntot; i += 32) {                 // predicated tail batch
        #pragma unroll
        for (int j = 0; j < 8; ++j) {
            const int slot = i + 2 * (2 * j + pr);
            if (slot < ntot) {
                const float4 v = *(const float4*)(Xs + (size_t)list[slot] * DIM);
                acc[j].x += v.x; acc[j].y += v.y;
                acc[j].z += v.z; acc[j].w += v.w;
            }
        }
    }
    float4 a;
    a.x = ((acc[0].x + acc[1].x) + (acc[2].x + acc[3].x))
        + ((acc[4].x + acc[5].x) + (acc[6].x + acc[7].x));
    a.y = ((acc[0].y + acc[1].y) + (acc[2].y + acc[3].y))
        + ((acc[4].y + acc[5].y) + (acc[6].y + acc[7].y));
    a.z = ((acc[0].z + acc[1].z) + (acc[2].z + acc[3].z))
        + ((acc[4].z + acc[5].z) + (acc[6].z + acc[7].z));
    a.w = ((acc[0].w + acc[1].w) + (acc[2].w + acc[3].w))
        + ((acc[4].w + acc[5].w) + (acc[6].w + acc[7].w));
    sred[w][pr][c4] = a;
    __syncthreads();

    // fold (parity, half-wave), write partial
    const int cs2 = tid >> 7, c2 = tid & 127;
    const int q4 = c2 >> 2, qc = c2 & 3;
    const float* s0 = (const float*)&sred[cs2][0][q4];
    const float* s1 = (const float*)&sred[cs2][1][q4];
    const float* s2 = (const float*)&sred[cs2 + 4][0][q4];
    const float* s3 = (const float*)&sred[cs2 + 4][1][q4];
    partial[(size_t)(h * KC + k) * DIM + cs2 * 128 + c2] =
        (s0[qc] + s1[qc]) + (s2[qc] + s3[qc]);
    if (tid == 0) pcount[h * KC + k] = ntot;
}

// ---------------------------------------------------------------------------
// Kernel B: fold 4 quarter-partials -> r[K][D]; norm, kappa, logk, ive.
// 128 blocks x 512 threads (thread = column).
// ---------------------------------------------------------------------------
__global__ __launch_bounds__(512) void vmf_reduce2(
    const float* __restrict__ partial, const int* __restrict__ pcount,
    float* __restrict__ r, float* __restrict__ kappa, float* __restrict__ logk,
    float* __restrict__ bes, float* __restrict__ innorm)
{
    const int k = blockIdx.x, t = threadIdx.x;
    float s = 0.f;
    #pragma unroll
    for (int hh = 0; hh < NPART; ++hh)
        s += partial[(size_t)(hh * KC + k) * DIM + t];
    r[(size_t)k * DIM + t] = s;

    float ss = s * s;
    for (int off = 32; off; off >>= 1) ss += __shfl_down(ss, off);
    __shared__ float wsum[8];
    if ((t & 63) == 0) wsum[t >> 6] = ss;
    __syncthreads();
    if (t == 0) {
        float tot = 0.f;
        #pragma unroll
        for (int q = 0; q < 8; ++q) tot += wsum[q];
        const float norm = sqrtf(tot);
        int nki = 0;
        #pragma unroll
        for (int hh = 0; hh < NPART; ++hh) nki += pcount[hh * KC + k];
        const float nk = (float)nki;
        const float rb = norm / nk;
        float kap = ((float)DIM * rb - rb * rb * rb) / (1.f - rb * rb);
        if (rb > 0.9f) kap = -0.4f + 1.39f * rb + 0.43f / (1.f - rb);
        kappa[k] = kap;
        logk[k]  = logf(kap);
        const float v  = 255.5f;
        const float zz = kap / v;
        const float sq = sqrtf(1.f + zz * zz);
        const float tt = 1.f / sq, t2 = tt * tt;
        const float eta = sq + logf(zz / (1.f + sq));
        const float u1 = (3.f * tt - 5.f * tt * t2) / 24.f;
        const float u2 = (81.f * t2 - 462.f * t2 * t2 + 385.f * t2 * t2 * t2) / 1152.f;
        const float u3 = (30375.f * tt * t2 - 369603.f * tt * t2 * t2
                    + 765765.f * tt * t2 * t2 * t2
                    - 425425.f * tt * t2 * t2 * t2 * t2) / 414720.f;
        const float series = 1.f + u1 / v + u2 / (v * v) + u3 / (v * v * v);
        const float ive = expf(v * eta - kap) * series
                    / (sqrtf(2.f * 3.14159265358979f * v) * sqrtf(sq));
        bes[k] = ive;
        innorm[k] = 1.f / norm;
    }
}

// ---------------------------------------------------------------------------
// Kernel C: block i computes kl[i][j]^2 for all j, reduces to rowsum[i].
// ---------------------------------------------------------------------------
__global__ __launch_bounds__(128) void vmf_gram(
    const float* __restrict__ r, const float* __restrict__ kappa,
    const float* __restrict__ logk, const float* __restrict__ bes,
    const float* __restrict__ innorm, float* __restrict__ rowsum)
{
    const int i = blockIdx.x, j = threadIdx.x;
    __shared__ float mui[DIM];
    const float inv_i = innorm[i];
    for (int d = j; d < DIM; d += 128) mui[d] = r[(size_t)i * DIM + d] * inv_i;
    __syncthreads();

    const float4* rj = (const float4*)(r + (size_t)j * DIM);
    float acc = 0.f;
    #pragma unroll 4
    for (int d4 = 0; d4 < DIM / 4; ++d4) {
        float4 v = rj[d4];
        acc += mui[d4 * 4 + 0] * v.x + mui[d4 * 4 + 1] * v.y
             + mui[d4 * 4 + 2] * v.z + mui[d4 * 4 + 3] * v.w;
    }
    const float dot = acc * innorm[j];
    const float dstar = 255.5f;
    float kl = dstar * (logk[j] - logk[i]) - kappa[i] + bes[i] - bes[j]
             + kappa[j] * dot;
    float v2 = kl * kl;
    for (int off = 32; off; off >>= 1) v2 += __shfl_down(v2, off);
    __shared__ float ws2[2];
    if ((j & 63) == 0) ws2[j >> 6] = v2;
    __syncthreads();
    if (j == 0) rowsum[i] = ws2[0] + ws2[1];
}

// ---------------------------------------------------------------------------
// Kernel D: sum 128 row sums -> out[0] = total / K^2
// ---------------------------------------------------------------------------
__global__ __launch_bounds__(128) void vmf_final(
    const float* __restrict__ rowsum, float* __restrict__ out)
{
    const int t = threadIdx.x;
    float v = rowsum[t];
    for (int off = 32; off; off >>= 1) v += __shfl_down(v, off);
    __shared__ float w[2];
    if ((t & 63) == 0) w[t >> 6] = v;
    __syncthreads();
    if (t == 0) out[0] = (w[0] + w[1]) / (float)(KC * KC);
}

extern "C" void kernel_launch(void* const* d_in, const int* in_sizes, int n_in,
                              void* d_out, int out_size, void* d_ws, size_t ws_size,
                              hipStream_t stream)
{
    const float* X = (const float*)d_in[0];
    const int*   y = (const int*)d_in[1];
    float* out = (float*)d_out;
    float* ws  = (float*)d_ws;

    // workspace layout (float units) -- NOTE: pcount is 512 ints
    // (66176..66687); partial starts at 67584 to stay clear (R5 had them
    // overlapping -> int/float aliasing -> negative nk -> logf(neg) = NaN).
    float* r      = ws;                         // 0      .. 65535
    float* kappa  = ws + 65536;                 // 65536  .. 65663
    float* logk   = ws + 65536 + 128;           // 65664  .. 65791
    float* bes    = ws + 65536 + 256;           // 65792  .. 65919
    float* innorm = ws + 65536 + 384;           // 65920  .. 66047
    float* rowsum = ws + 65536 + 512;           // 66048  .. 66175
    int*   pcount = (int*)(ws + 66176);         // 66176  .. 66687 (ints)
    float* partial = ws + 67584;                // 67584  .. 329727

    vmf_scan_sum<<<KC * NPART, 512, 0, stream>>>(X, y, partial, pcount);
    vmf_reduce2<<<KC, 512, 0, stream>>>(partial, pcount, r, kappa, logk, bes,
                                        innorm);
    vmf_gram<<<KC, 128, 0, stream>>>(r, kappa, logk, bes, innorm, rowsum);
    vmf_final<<<1, 128, 0, stream>>>(rowsum, out);
}